// Round 2
// 93.759 us; speedup vs baseline: 1.0693x; 1.0693x over previous
//
#include <hip/hip_runtime.h>

#define IN_DIM   256
#define OUT_DIM  256
#define NKNOT    19                    // NUM_KNOTS-1 spline segments
#define NCOL     (IN_DIM * NKNOT)      // 4864 (i,k) columns
#define CPQ      1216                  // columns per i-quarter (64*19)
#define SLICE_U4 (CPQ * 64)            // 77824 uint4 per (quarter,o_half) slice
#define X_MIN_C  (-5.0f)
#define H_C      (10.0f / 19.0f)
#define INV_H_C  (19.0f / 10.0f)

typedef __fp16 half2_t __attribute__((ext_vector_type(2)));

// pack two f32 -> f16 pair (RTZ), low = x, high = y  (1 instr: v_cvt_pkrtz_f16_f32)
__device__ __forceinline__ unsigned int pk_f16(float x, float y) {
    return __builtin_bit_cast(unsigned int, __builtin_amdgcn_cvt_pkrtz(x, y));
}

// acc += w.lo*c.lo + w.hi*c.hi   (1 instr: v_dot2_f32_f16, f32 accumulate)
__device__ __forceinline__ float fdot2(unsigned int w, unsigned int c, float acc) {
#if __has_builtin(__builtin_amdgcn_fdot2)
    return __builtin_amdgcn_fdot2(__builtin_bit_cast(half2_t, w),
                                  __builtin_bit_cast(half2_t, c), acc, false);
#else
    half2_t a = __builtin_bit_cast(half2_t, w);
    half2_t b = __builtin_bit_cast(half2_t, c);
    return acc + (float)a.x * (float)b.x + (float)a.y * (float)b.y;
#endif
}

// ---------------------------------------------------------------------------
// Kernel 1: transpose + pack to f16.
//  coeffs [o=256][c=4864] float4 -> per-slice uint4 entries:
//   slice s = quarter*2 + o_half;  entry (c_local, og2), og2 in [0,64):
//   Q = { pk(a,b), pk(c,d) } of o = o_half*128 + 2*og2  |  same of o+1.
//  Entry index within slice = c_local*64 + og2.
// ---------------------------------------------------------------------------
__global__ __launch_bounds__(256) void transpose_pack(
        const float4* __restrict__ src, uint4* __restrict__ dst) {
    __shared__ uint2 tile[64][65];           // [c_local][o_local] f16 quads, +1 pad
    const int c0 = (blockIdx.x % 76) * 64;   // no quarter straddle: 1216 % 64 == 0
    const int r0 = (blockIdx.x / 76) * 64;   // o-tile base
    const int tx = threadIdx.x & 63;
    const int ty = threadIdx.x >> 6;

    #pragma unroll
    for (int jj = 0; jj < 16; ++jj) {
        const int r = ty * 16 + jj;
        const float4 v = src[(size_t)(r0 + r) * NCOL + (size_t)(c0 + tx)];
        uint2 p;
        p.x = pk_f16(v.x, v.y);              // (a,b)
        p.y = pk_f16(v.z, v.w);              // (c,d)
        tile[tx][r] = p;
    }
    __syncthreads();

    const int quarter  = c0 / CPQ;
    const int clbase   = c0 - quarter * CPQ;
    const int o_half   = r0 >> 7;
    const int og2_base = (r0 & 127) >> 1;    // 0 or 32
    uint4* base = dst + (size_t)(quarter * 2 + o_half) * SLICE_U4;

    #pragma unroll
    for (int jj = 0; jj < 8; ++jj) {
        const int p     = jj * 256 + threadIdx.x;
        const int cl    = p >> 5;            // 0..63
        const int og2l  = p & 31;            // 0..31
        const uint2 t0  = tile[cl][og2l * 2];      // o even
        const uint2 t1  = tile[cl][og2l * 2 + 1];  // o odd
        base[(size_t)(clbase + cl) * 64 + og2_base + og2l] =
            make_uint4(t0.x, t0.y, t1.x, t1.y);
    }
}

// ---------------------------------------------------------------------------
// Kernel 2: partial gather+eval. 256 thr = 4 bs x 64 og2; thread owns 2 o's.
//  Per i: broadcast {k*64, pk(1,t), pk(t2,t3)} from LDS + ONE fully-dense
//  dwordx4 (wave reads contiguous 1 KB) -> 4 v_dot2_f32_f16.
//  grid = 8 slices x (B/4) bgrps = 2048 blocks; s = blockIdx&7 keeps the
//  1.24 MB slice pinned to one XCD's L2.
// ---------------------------------------------------------------------------
__global__ __launch_bounds__(256, 4) void kan_partial(
        const float* __restrict__ x,
        const uint4* __restrict__ Ct,
        float2*      __restrict__ part,     // float layout: [4][B][256] linear o
        int B) {
    __shared__ int4 s_tk[4 * 64];           // {k*64, pk(1,t), pk(t2,t3), 0}

    const int s       = blockIdx.x & 7;
    const int o_half  = s & 1;
    const int quarter = s >> 1;
    const int bgrp    = blockIdx.x >> 3;
    const int tid     = threadIdx.x;

    {
        const int col = tid & 63;
        const int bs  = tid >> 6;
        const float xv = x[(bgrp * 4 + bs) * IN_DIM + quarter * 64 + col];
        const float f  = (xv - X_MIN_C) * INV_H_C;
        int idx = (int)floorf(f);
        idx = idx < 0 ? 0 : (idx > NKNOT - 1 ? NKNOT - 1 : idx);
        const float t  = xv - (X_MIN_C + (float)idx * H_C);
        const float t2 = t * t;
        const float t3 = t2 * t;
        s_tk[bs * 64 + col] = make_int4(idx * 64,
                                        (int)pk_f16(1.0f, t),
                                        (int)pk_f16(t2, t3), 0);
    }
    __syncthreads();

    const int og2 = tid & 63;
    const int bs  = tid >> 6;
    const uint4* base = Ct + (size_t)s * SLICE_U4;   // SGPR base; 32-bit voffset
    const int4* tkp = s_tk + bs * 64;

    float y0 = 0.f, y1 = 0.f;

    #pragma unroll 8
    for (int ii = 0; ii < 64; ++ii) {
        const int4 tk = tkp[ii];                     // wave-uniform broadcast
        const uint4 Q = base[og2 + ii * 1216 + tk.x];
        const unsigned int w01 = (unsigned int)tk.y; // (1, t)
        const unsigned int w23 = (unsigned int)tk.z; // (t^2, t^3)
        y0 = fdot2(w01, Q.x, y0);                    // a + b t      (o even)
        y0 = fdot2(w23, Q.y, y0);                    // c t^2 + d t^3
        y1 = fdot2(w01, Q.z, y1);                    // (o odd)
        y1 = fdot2(w23, Q.w, y1);
    }

    const int b = bgrp * 4 + bs;
    // float2 index -> float offset quarter*B*256 + b*256 + (o_half*128 + 2*og2)
    part[(size_t)quarter * (B * 128) + (size_t)b * 128 + o_half * 64 + og2] =
        make_float2(y0, y1);
}

// ---------------------------------------------------------------------------
// Kernel 3: out = sum of 4 quarter-partials + bias  (float4) — layout is
// linear in o, identical to previous version.
// ---------------------------------------------------------------------------
__global__ __launch_bounds__(256) void kan_reduce(
        const float4* __restrict__ part,
        const float4* __restrict__ bias4,
        float4*       __restrict__ out,
        int n4) {
    const int n = blockIdx.x * 256 + threadIdx.x;
    if (n < n4) {
        const float4 p0 = part[n];
        const float4 p1 = part[n4 + n];
        const float4 p2 = part[2 * n4 + n];
        const float4 p3 = part[3 * n4 + n];
        const float4 bv = bias4[n & 63];
        float4 r;
        r.x = (p0.x + p1.x) + (p2.x + p3.x) + bv.x;
        r.y = (p0.y + p1.y) + (p2.y + p3.y) + bv.y;
        r.z = (p0.z + p1.z) + (p2.z + p3.z) + bv.z;
        r.w = (p0.w + p1.w) + (p2.w + p3.w) + bv.w;
        out[n] = r;
    }
}

// ---------------------------------------------------------------------------
extern "C" void kernel_launch(void* const* d_in, const int* in_sizes, int n_in,
                              void* d_out, int out_size, void* d_ws, size_t ws_size,
                              hipStream_t stream) {
    const float* x      = (const float*)d_in[0];   // (B, 256) fp32
    const float* coeffs = (const float*)d_in[1];   // (256, 256, 19, 4) fp32
    const float* bias   = (const float*)d_in[2];   // (256,) fp32
    float*       out    = (float*)d_out;           // (B, 256) fp32

    const int B = in_sizes[0] / IN_DIM;            // 1024
    uint4* Ct   = (uint4*)d_ws;                    // 9.96 MB f16 slices
    float* part = (float*)((char*)d_ws + (16u << 20)); // 4 MB

    transpose_pack<<<304, 256, 0, stream>>>((const float4*)coeffs, Ct);

    kan_partial<<<(B / 4) * 8, 256, 0, stream>>>(x, Ct, (float2*)part, B);

    const int n4 = B * OUT_DIM / 4;                // B*64
    kan_reduce<<<(n4 + 255) / 256, 256, 0, stream>>>(
        (const float4*)part, (const float4*)bias, (float4*)out, n4);
}